// Round 6
// baseline (94.629 us; speedup 1.0000x reference)
//
#include <hip/hip_runtime.h>

namespace {

typedef float v2f __attribute__((ext_vector_type(2)));

constexpr int T_LEN = 262144;   // samples per batch
constexpr int NF    = 1024;     // frames per batch
constexpr float INV1024 = 1.0f / 1024.0f;

// Single-wave workgroup: LDS ops execute in program order for the wave ->
// compiler reordering fence only, no s_barrier / vmcnt(0) drain.
#define LDS_FENCE() asm volatile("" ::: "memory")

// Sum across each quad (4 overlap slots): two DPP quad_perm add stages.
__device__ __forceinline__ float qsum(float x) {
    x += __int_as_float(__builtin_amdgcn_update_dpp(
             0, __float_as_int(x), 0xB1, 0xF, 0xF, true));
    x += __int_as_float(__builtin_amdgcn_update_dpp(
             0, __float_as_int(x), 0x4E, 0xF, 0xF, true));
    return x;
}

// 4 samples of order-22 IIR (transposed DF-II), state packed (s[j], s[j+11]).
__device__ __forceinline__ void iir4(const float4& x4, v2f (&sv)[11],
                                     const v2f (&mav)[11], float gv,
                                     float (&yo)[4]) {
    const float xv[4] = {x4.x, x4.y, x4.z, x4.w};
    #pragma unroll
    for (int u = 0; u < 4; ++u) {
        float y   = fmaf(gv, xv[u], sv[0].x);
        float s11 = sv[0].y;
        v2f yy = (v2f){y, y};
        #pragma unroll
        for (int j = 0; j < 10; ++j)
            sv[j] = __builtin_elementwise_fma(mav[j], yy, sv[j + 1]);
        sv[10].x = fmaf(mav[10].x, y, s11);
        sv[10].y = mav[10].y * y;
        yo[u] = y;
    }
}

// Out phase: 8 sub-blocks of 16 samples. x from LDS (conflict-free b128,
// quad-broadcast), hann weight via v_cos, quad DPP overlap-add, result to
// LDS staging (predicated: one lane per task per sub-block).
template <bool EDGE>
__device__ __forceinline__ void outphase(const float* __restrict__ exo,
                                         float* __restrict__ oto,
                                         v2f (&sv)[11], const v2f (&mav)[11],
                                         float gv, float rev, float cA, float cB,
                                         int kk) {
    #pragma unroll 1
    for (int sb = 0; sb < 8; ++sb) {
        const bool st = (kk == (sb >> 1));
        #pragma unroll
        for (int qg = 0; qg < 4; ++qg) {
            float4 x4 = *(const float4*)(exo + sb * 16 + qg * 4);
            float y[4];
            iir4(x4, sv, mav, gv, y);
            float o[4];
            #pragma unroll
            for (int u = 0; u < 4; ++u) {
                float c = __builtin_amdgcn_cosf(rev);   // cos(2*pi*rev)
                rev += INV1024;
                float wl = fmaf(cA, c, cB);             // mval-scaled hann
                if (EDGE) o[u] = qsum(wl * y[u]) * __builtin_amdgcn_rcpf(qsum(wl));
                else      o[u] = qsum(wl * y[u]);       // interior: wsum==2 folded
            }
            if (st) *(float4*)(oto + sb * 16 + qg * 4) =
                        make_float4(o[0], o[1], o[2], o[3]);
        }
    }
}

// Per batch: 2048 output blocks of 128 (i = 3..2050, out base i*128-384 tiles
// [0,262144)). Wave = 16 consecutive blocks; quad slot kk runs frame f=(i>>1)-kk
// (128 warm + 128 out). ALL global traffic is wave-coalesced through LDS:
// ex span 2176 floats in, out span 2048 floats out, 12 frames' coeffs in.
__global__ __launch_bounds__(64, 2)
void lpc_ola_kernel(const float* __restrict__ ex,
                    const float* __restrict__ gain,
                    const float* __restrict__ a,
                    float* __restrict__ out)
{
    // lidx = idx + 4*(idx>>7): +4-float pad per 128 -> the 128-stride per-task
    // layout lands on distinct banks (task jl -> bank jl*33%32 = jl).
    __shared__ __align__(16) float exs[2240];   // 2176 span, padded
    __shared__ __align__(16) float outs[2108];  // 2048 span, padded
    __shared__ __align__(16) float cfs[288];    // 12 frames x (22 coeffs + gain + pad)

    const int lane = threadIdx.x;
    const int w    = blockIdx.x;
    const int wloc = w & 127;
    const int b    = w >> 7;
    const bool edge = (wloc == 0) | (wloc == 127);

    const int i0    = wloc * 16 + 3;        // first task (odd)
    const int xbase = i0 * 128 - 512;       // ex coord of span start (mult of 128)
    const int obase = i0 * 128 - 384;       // out coord of flush start
    const float* exb  = ex  + (size_t)b * T_LEN;
    float*       outb = out + (size_t)b * T_LEN;

    // ---- stage ex: 9 coalesced wave-loads (last half-wave) ----
    #pragma unroll
    for (int r = 0; r < 9; ++r) {
        const int idx = r * 256 + lane * 4;
        if (idx < 2176) {
            const int g = xbase + idx;
            float4 v = make_float4(0.f, 0.f, 0.f, 0.f);
            if ((unsigned)g < (unsigned)T_LEN) v = *(const float4*)(exb + g);
            *(float4*)&exs[idx + ((idx >> 7) << 2)] = v;
        }
    }
    // ---- stage coeffs: frames fbase..fbase+11, 24 floats each ----
    const int fbase = wloc * 8 - 2;
    #pragma unroll
    for (int r = 0; r < 5; ++r) {
        const int idx = r * 64 + lane;
        if (idx < 288) {
            const int q = (idx * 2731) >> 16;        // idx / 24
            const int c = idx - q * 24;
            const int f = fbase + q;
            float vv = 0.f;
            if ((unsigned)f < (unsigned)NF) {
                if (c < 22)       vv = a[(size_t)(b * NF + f) * 22 + c];
                else if (c == 22) vv = gain[b * NF + f];
            }
            cfs[idx] = vv;
        }
    }
    LDS_FENCE();

    // ---- per-lane setup ----
    const int kk = lane & 3;
    const int jl = lane >> 2;
    const int i  = i0 + jl;
    const int fi = i >> 1;
    const int f  = fi - kk;
    const float mval = ((unsigned)f < (unsigned)NF) ? 1.f : 0.f;
    const int q  = ((jl + 1) >> 1) + 3 - kk;        // f - fbase, in [0,11]
    const float* cf = cfs + q * 24;
    const float gv = cf[22];                         // 0 for invalid frames

    v2f mav[11];
    {
        float man[22];
        #pragma unroll
        for (int j = 0; j < 11; ++j) {
            float2 t = ((const float2*)cf)[j];
            man[2 * j] = -t.x; man[2 * j + 1] = -t.y;
        }
        #pragma unroll
        for (int j = 0; j < 11; ++j) mav[j] = (v2f){man[j], man[j + 11]};
    }
    v2f sv[11];
    #pragma unroll
    for (int j = 0; j < 11; ++j) sv[j] = (v2f){0.f, 0.f};

    const int e   = i & 1;
    const int m0k = kk * 256 + (e << 7);     // frame-local idx of out sample 0
    const float rev = (float)m0k * INV1024;
    const float scale = edge ? 0.5f : 0.25f;
    const float cA = -scale * mval, cB = scale * mval;

    // ---- warm: 128 samples from LDS (lidx = jl*132 + t), ping-pong ----
    const float* exw = exs + jl * 132;
    {
        float yd[4];
        float4 Xa = *(const float4*)(exw);
        #pragma unroll 1
        for (int g = 0; g < 16; ++g) {
            float4 Xb = *(const float4*)(exw + g * 8 + 4);
            iir4(Xa, sv, mav, gv, yd);
            if (g < 15) Xa = *(const float4*)(exw + g * 8 + 8);
            iir4(Xb, sv, mav, gv, yd);
        }
    }

    // ---- out: 128 samples; x at lidx = jl*132 + 132 + t' ----
    const float* exo = exs + jl * 132 + 132;
    float* oto = outs + jl * 132;
    if (!edge) outphase<false>(exo, oto, sv, mav, gv, rev, cA, cB, kk);
    else       outphase<true >(exo, oto, sv, mav, gv, rev, cA, cB, kk);

    LDS_FENCE();
    // ---- flush: 8 coalesced wave-stores, proven in-bounds ----
    #pragma unroll
    for (int r = 0; r < 8; ++r) {
        const int gi = r * 256 + lane * 4;
        float4 v = *(const float4*)&outs[gi + ((gi >> 7) << 2)];
        *(float4*)(outb + obase + gi) = v;
    }
}

} // namespace

extern "C" void kernel_launch(void* const* d_in, const int* in_sizes, int n_in,
                              void* d_out, int out_size, void* d_ws, size_t ws_size,
                              hipStream_t stream)
{
    (void)in_sizes; (void)n_in; (void)out_size; (void)d_ws; (void)ws_size;
    const float* ex   = (const float*)d_in[0];
    const float* gain = (const float*)d_in[1];
    const float* a    = (const float*)d_in[2];
    float* out        = (float*)d_out;

    dim3 grid(2048);   // 16 batches x 128 waves; 8 single-wave workgroups per CU
    dim3 block(64);
    hipLaunchKernelGGL(lpc_ola_kernel, grid, block, 0, stream, ex, gain, a, out);
}

// Round 7
// 90.054 us; speedup vs baseline: 1.0508x; 1.0508x over previous
//
#include <hip/hip_runtime.h>

namespace {

typedef _Float16 h2 __attribute__((ext_vector_type(2)));

constexpr int T_LEN = 262144;   // samples per batch
constexpr int NF    = 1024;     // frames per batch
constexpr float INV1024 = 1.0f / 1024.0f;
constexpr int WSTRIDE = 136;    // floats per (kk,e) row: 16B-aligned, banks +8/row

// Single-wave workgroup: per-wave in-order LDS -> compiler fence only.
#define LDS_FENCE() asm volatile("" ::: "memory")

// Sum across each quad (4 overlap slots): two DPP quad_perm add stages.
__device__ __forceinline__ float qsum(float x) {
    x += __int_as_float(__builtin_amdgcn_update_dpp(
             0, __float_as_int(x), 0xB1, 0xF, 0xF, true));
    x += __int_as_float(__builtin_amdgcn_update_dpp(
             0, __float_as_int(x), 0x4E, 0xF, 0xF, true));
    return x;
}

template <bool CK>
__device__ __forceinline__ void ld4(const float* __restrict__ exb, int xi,
                                    float4 (&buf)[4]) {
    #pragma unroll
    for (int q = 0; q < 4; ++q) {
        const int idx = xi + q * 4;
        if (CK) {   // only wave 0 of a batch can touch idx<0; upper bound proven
            float4 v = make_float4(0.f, 0.f, 0.f, 0.f);
            if (idx >= 0) v = *(const float4*)(exb + idx);
            buf[q] = v;
        } else {
            buf[q] = *(const float4*)(exb + idx);
        }
    }
}

// 4 samples of order-22 IIR (transposed DF-II). State packed as f16 pairs
// (s[j], s[j+11]) -> 11 full-rate v_pk_fma_f16 per sample (vs 10 two-pass
// v_pk_fma_f32 = 40 cyc). y kept in fp32 (gain*x + s0 accumulated fp32).
__device__ __forceinline__ void iir4(const float4& x4, h2 (&sv)[11],
                                     const h2 (&mav)[11], float gv,
                                     float (&yo)[4]) {
    const float xv[4] = {x4.x, x4.y, x4.z, x4.w};
    #pragma unroll
    for (int u = 0; u < 4; ++u) {
        const h2 t0 = sv[0];
        float y = fmaf(gv, xv[u], (float)t0.x);
        _Float16 yh = (_Float16)y;
        h2 yy = (h2){yh, yh};
        #pragma unroll
        for (int j = 0; j < 10; ++j)
            sv[j] = __builtin_elementwise_fma(mav[j], yy, sv[j + 1]);
        sv[10] = __builtin_elementwise_fma(mav[10], yy,
                                           (h2){t0.y, (_Float16)0.f});
        yo[u] = y;
    }
}

__device__ __forceinline__ void procW(const float4 (&buf)[4], h2 (&sv)[11],
                                      const h2 (&mav)[11], float gv) {
    float yd[4];
    #pragma unroll
    for (int q = 0; q < 4; ++q) iir4(buf[q], sv, mav, gv, yd);
}

// Interior out: weights (0.25*(1-cos)) preloaded from LDS; sum/2 folded in.
__device__ __forceinline__ void procOi(const float4 (&buf)[4], h2 (&sv)[11],
                                       const h2 (&mav)[11], float gv,
                                       const float* __restrict__ wrow, int t0,
                                       bool st, float* __restrict__ outp) {
    float4 w4[4];
    #pragma unroll
    for (int q = 0; q < 4; ++q) w4[q] = *(const float4*)(wrow + t0 + q * 4);
    #pragma unroll
    for (int q = 0; q < 4; ++q) {
        float y[4];
        iir4(buf[q], sv, mav, gv, y);
        const float wv[4] = {w4[q].x, w4[q].y, w4[q].z, w4[q].w};
        float o[4];
        #pragma unroll
        for (int u = 0; u < 4; ++u) o[u] = qsum(wv[u] * y[u]);
        if (st) *(float4*)(outp + q * 4) = make_float4(o[0], o[1], o[2], o[3]);
    }
}

// Edge out (32 of 2048 waves): per-sample cos, masked wsum, rcp normalize.
__device__ __forceinline__ void procOe(const float4 (&buf)[4], h2 (&sv)[11],
                                       const h2 (&mav)[11], float gv,
                                       float& rev, float cA, float cB,
                                       bool st, float* __restrict__ outp) {
    #pragma unroll
    for (int q = 0; q < 4; ++q) {
        float y[4];
        iir4(buf[q], sv, mav, gv, y);
        float o[4];
        #pragma unroll
        for (int u = 0; u < 4; ++u) {
            float c  = __builtin_amdgcn_cosf(rev);  // cos(2*pi*rev)
            rev += INV1024;
            float wl = fmaf(cA, c, cB);             // mval * hann(m)
            o[u] = qsum(wl * y[u]) * __builtin_amdgcn_rcpf(qsum(wl));
        }
        if (st) *(float4*)(outp + q * 4) = make_float4(o[0], o[1], o[2], o[3]);
    }
}

// Per batch: 2048 output blocks of 128 samples (i = 3..2050; out base i*128-384
// tiles [0, 262144)). Quad slot kk runs frame f = (i>>1)-kk: 128 warm + 128 out
// samples. Depth-3 prefetch over 4 rotating 16-sample buffers. No barriers.
__global__ __launch_bounds__(64, 2)
void lpc_ola_kernel(const float* __restrict__ ex,
                    const float* __restrict__ gain,
                    const float* __restrict__ a,
                    float* __restrict__ out)
{
    __shared__ __align__(16) float wq[8 * WSTRIDE];  // [kk*2+e][128] scaled hann

    const int lane = threadIdx.x;
    const int w    = blockIdx.x;
    const int wloc = w & 127;
    const bool chk  = (wloc == 0);
    const bool edge = (wloc == 0) | (wloc == 127);

    // Build weight table: W(m) = 0.25*(1 - cos(2*pi*m/1024)) = 0.5*hann(m).
    #pragma unroll
    for (int ii = 0; ii < 16; ++ii) {
        int m = lane * 16 + ii;
        float c = __builtin_amdgcn_cosf((float)m * INV1024);
        wq[(m >> 7) * WSTRIDE + (m & 127)] = 0.25f * (1.0f - c);
    }
    LDS_FENCE();

    const int kk = lane & 3;          // overlap slot within quad
    const int jl = lane >> 2;         // task-in-wave
    const int tau = w * 16 + jl;
    const int b  = tau >> 11;
    const int i  = (tau & 2047) + 3;
    const int fi = i >> 1;
    const int f  = fi - kk;
    const bool fv = (unsigned)f < (unsigned)NF;
    const int fc = fv ? f : 0;
    const float mval = fv ? 1.f : 0.f;
    const float gv   = fv ? gain[b * NF + fc] : 0.f;

    h2 mav[11];
    {
        const float2* ap = (const float2*)(a + (size_t)(b * NF + fc) * 22);
        float man[22];
        #pragma unroll
        for (int j = 0; j < 11; ++j) {
            float2 t = ap[j];
            man[2 * j] = -t.x; man[2 * j + 1] = -t.y;
        }
        #pragma unroll
        for (int j = 0; j < 11; ++j)
            mav[j] = (h2){(_Float16)man[j], (_Float16)man[j + 11]};
    }
    h2 sv[11];
    #pragma unroll
    for (int j = 0; j < 11; ++j) sv[j] = (h2){(_Float16)0.f, (_Float16)0.f};

    const float* exb = ex + (size_t)b * T_LEN;
    int xi = i * 128 - 512;                      // first warm sample (kk-indep)
    const int e    = i & 1;
    const int m0k  = kk * 256 + (e << 7);        // frame-local idx of out sample 0
    const float* wrow = wq + (((kk << 1) | e) * WSTRIDE);
    float rev = (float)m0k * INV1024;            // edge path only
    const float cA = -0.5f * mval, cB = 0.5f * mval;
    float* outp0 = out + (size_t)b * T_LEN + (i * 128 - 384);

    float4 A[4], B[4], C[4], D[4];

    // preload sub-blocks 0..3 (depth-3 pipeline fill)
    if (chk) {
        ld4<true>(exb, xi, A); xi += 16; ld4<true>(exb, xi, B); xi += 16;
        ld4<true>(exb, xi, C); xi += 16; ld4<true>(exb, xi, D); xi += 16;
    } else {
        ld4<false>(exb, xi, A); xi += 16; ld4<false>(exb, xi, B); xi += 16;
        ld4<false>(exb, xi, C); xi += 16; ld4<false>(exb, xi, D); xi += 16;
    }

    // ---- warm: subs 0..7, refilling subs 4..11 ----
    #pragma unroll 1
    for (int m = 0; m < 2; ++m) {
        procW(A, sv, mav, gv);
        if (chk) ld4<true>(exb, xi, A); else ld4<false>(exb, xi, A); xi += 16;
        procW(B, sv, mav, gv);
        if (chk) ld4<true>(exb, xi, B); else ld4<false>(exb, xi, B); xi += 16;
        procW(C, sv, mav, gv);
        if (chk) ld4<true>(exb, xi, C); else ld4<false>(exb, xi, C); xi += 16;
        procW(D, sv, mav, gv);
        if (chk) ld4<true>(exb, xi, D); else ld4<false>(exb, xi, D); xi += 16;
    }
    // A..D now hold out sub-blocks 0..3; xi points at sub 4's data.

    // ---- out: 8 sub-blocks of 16; refills (subs 4..7) proven in-bounds ----
    if (!edge) {
        #pragma unroll 1
        for (int m2 = 0; m2 < 2; ++m2) {
            const bool lf = (m2 == 0);
            const int sb = m2 * 4;
            procOi(A, sv, mav, gv, wrow, (sb + 0) * 16, kk == ((sb + 0) >> 1),
                   outp0 + (sb + 0) * 16);
            if (lf) { ld4<false>(exb, xi, A); xi += 16; }
            procOi(B, sv, mav, gv, wrow, (sb + 1) * 16, kk == ((sb + 1) >> 1),
                   outp0 + (sb + 1) * 16);
            if (lf) { ld4<false>(exb, xi, B); xi += 16; }
            procOi(C, sv, mav, gv, wrow, (sb + 2) * 16, kk == ((sb + 2) >> 1),
                   outp0 + (sb + 2) * 16);
            if (lf) { ld4<false>(exb, xi, C); xi += 16; }
            procOi(D, sv, mav, gv, wrow, (sb + 3) * 16, kk == ((sb + 3) >> 1),
                   outp0 + (sb + 3) * 16);
            if (lf) { ld4<false>(exb, xi, D); xi += 16; }
        }
    } else {
        #pragma unroll 1
        for (int m2 = 0; m2 < 2; ++m2) {
            const bool lf = (m2 == 0);
            const int sb = m2 * 4;
            procOe(A, sv, mav, gv, rev, cA, cB, kk == ((sb + 0) >> 1),
                   outp0 + (sb + 0) * 16);
            if (lf) { ld4<false>(exb, xi, A); xi += 16; }
            procOe(B, sv, mav, gv, rev, cA, cB, kk == ((sb + 1) >> 1),
                   outp0 + (sb + 1) * 16);
            if (lf) { ld4<false>(exb, xi, B); xi += 16; }
            procOe(C, sv, mav, gv, rev, cA, cB, kk == ((sb + 2) >> 1),
                   outp0 + (sb + 2) * 16);
            if (lf) { ld4<false>(exb, xi, C); xi += 16; }
            procOe(D, sv, mav, gv, rev, cA, cB, kk == ((sb + 3) >> 1),
                   outp0 + (sb + 3) * 16);
            if (lf) { ld4<false>(exb, xi, D); xi += 16; }
        }
    }
}

} // namespace

extern "C" void kernel_launch(void* const* d_in, const int* in_sizes, int n_in,
                              void* d_out, int out_size, void* d_ws, size_t ws_size,
                              hipStream_t stream)
{
    (void)in_sizes; (void)n_in; (void)out_size; (void)d_ws; (void)ws_size;
    const float* ex   = (const float*)d_in[0];
    const float* gain = (const float*)d_in[1];
    const float* a    = (const float*)d_in[2];
    float* out        = (float*)d_out;

    dim3 grid(2048);   // 16 batches x 2048 half-blocks / 16 tasks per wave
    dim3 block(64);
    hipLaunchKernelGGL(lpc_ola_kernel, grid, block, 0, stream, ex, gain, a, out);
}